// Round 5
// baseline (1011.027 us; speedup 1.0000x reference)
//
#include <hip/hip_runtime.h>
#include <math.h>

#define NN 100000
#define NE 1600000
#define ET (NN + NE)
#define SH 7
#define NBK ((NN + 127) >> 7)  // 782 buckets of 128 nodes

typedef __attribute__((ext_vector_type(8))) __bf16 bf16x8;
typedef __attribute__((ext_vector_type(4))) float f32x4;

__device__ __forceinline__ unsigned short bf16rne(float f) {
  unsigned u = __float_as_uint(f);
  unsigned r = u + 0x7fffu + ((u >> 16) & 1u);
  return (unsigned short)(r >> 16);
}
__device__ __forceinline__ float bf16lo(unsigned u) {
  return __uint_as_float(u << 16);
}
__device__ __forceinline__ float bf16hi(unsigned u) {
  return __uint_as_float(u & 0xffff0000u);
}

// ---------------- fp32 -> bf16 cast ----------------
__global__ __launch_bounds__(256) void castbf_k(const float* __restrict__ in,
                                                unsigned short* __restrict__ out,
                                                int n4) {
  int i = blockIdx.x * 256 + threadIdx.x;
  if (i >= n4) return;
  float4 v = *(const float4*)(in + (size_t)i * 4);
  ushort4 u;
  u.x = bf16rne(v.x); u.y = bf16rne(v.y); u.z = bf16rne(v.z); u.w = bf16rne(v.w);
  *(ushort4*)(out + (size_t)i * 4) = u;
}

// ---------------- BN apply + ReLU + bf16 cast ----------------
__global__ __launch_bounds__(256) void bnc_k(const float* __restrict__ y,
                                             const float* __restrict__ scale,
                                             const float* __restrict__ shift,
                                             unsigned short* __restrict__ xb) {
  int i = blockIdx.x * 256 + threadIdx.x;
  if (i >= NN * 32) return;
  int c = (i * 4) & 127;
  float4 v = *(const float4*)(y + (size_t)i * 4);
  float4 sc = *(const float4*)(scale + c);
  float4 sh = *(const float4*)(shift + c);
  ushort4 u;
  u.x = bf16rne(fmaxf(fmaf(v.x, sc.x, sh.x), 0.f));
  u.y = bf16rne(fmaxf(fmaf(v.y, sc.y, sh.y), 0.f));
  u.z = bf16rne(fmaxf(fmaf(v.z, sc.z, sh.z), 0.f));
  u.w = bf16rne(fmaxf(fmaf(v.w, sc.w, sh.w), 0.f));
  *(ushort4*)(xb + (size_t)i * 4) = u;
}

// ---------------- MFMA GEMM: h2 = bf16(xb @ W) + fused alpha dots ----------------
template <int K, int H>
__global__ __launch_bounds__(256) void gemm_mfma_k(
    const unsigned short* __restrict__ xb, const float* __restrict__ W,
    const float* __restrict__ a_s, const float* __restrict__ a_d,
    unsigned short* __restrict__ h2, float* __restrict__ os,
    float* __restrict__ od) {
  __shared__ unsigned short xs[64 * K];
  __shared__ unsigned short Wt[128 * K];
  const int t = threadIdx.x;
  const int w = t >> 6;
  const int l = t & 63;
  const int l15 = l & 15, g = l >> 4;
  const int row0 = blockIdx.x * 64;

  for (int idx = t; idx < K * 128; idx += 256) {
    int k = idx >> 7, c = idx & 127;
    unsigned byteoff = ((unsigned)(c * K + k) * 2u) ^ ((unsigned)(c & 7) << 4);
    *(unsigned short*)((char*)Wt + byteoff) = bf16rne(W[idx]);
  }
  for (int idx = t; idx < 64 * (K / 8); idx += 256) {
    int r = idx / (K / 8);
    int c8 = (idx % (K / 8)) * 8;
    int grow = row0 + r;
    uint4 v = {0u, 0u, 0u, 0u};
    if (grow < NN) v = *(const uint4*)(xb + (size_t)grow * K + c8);
    unsigned byteoff = ((unsigned)(r * K + c8) * 2u) ^ ((unsigned)(r & 7) << 4);
    *(uint4*)((char*)xs + byteoff) = v;
  }
  __syncthreads();

  f32x4 acc[8];
#pragma unroll
  for (int ct = 0; ct < 8; ct++) acc[ct] = {0.f, 0.f, 0.f, 0.f};

  const int R = w * 16 + l15;
#pragma unroll
  for (int kc = 0; kc < K; kc += 32) {
    bf16x8 a = *(const bf16x8*)((const char*)xs +
        ((((unsigned)(R * K + kc + 8 * g)) * 2u) ^ ((unsigned)(R & 7) << 4)));
#pragma unroll
    for (int ct = 0; ct < 8; ct++) {
      int c = ct * 16 + l15;
      bf16x8 b = *(const bf16x8*)((const char*)Wt +
          ((((unsigned)(c * K + kc + 8 * g)) * 2u) ^ ((unsigned)(c & 7) << 4)));
      acc[ct] = __builtin_amdgcn_mfma_f32_16x16x32_bf16(a, b, acc[ct], 0, 0, 0);
    }
  }

  float as_l[8], ad_l[8];
#pragma unroll
  for (int ct = 0; ct < 8; ct++) {
    as_l[ct] = a_s[ct * 16 + l15];
    ad_l[ct] = a_d[ct * 16 + l15];
  }

#pragma unroll
  for (int r = 0; r < 4; r++) {
    int grow = row0 + w * 16 + 4 * g + r;
    bool ok = grow < NN;
    if (ok) {
#pragma unroll
      for (int ct = 0; ct < 8; ct++)
        h2[(size_t)grow * 128 + ct * 16 + l15] = bf16rne(acc[ct][r]);
    }
    if (H == 4) {
      float ps[4], pd[4];
#pragma unroll
      for (int hh = 0; hh < 4; hh++) {
        ps[hh] = acc[2 * hh][r] * as_l[2 * hh] + acc[2 * hh + 1][r] * as_l[2 * hh + 1];
        pd[hh] = acc[2 * hh][r] * ad_l[2 * hh] + acc[2 * hh + 1][r] * ad_l[2 * hh + 1];
      }
#pragma unroll
      for (int hh = 0; hh < 4; hh++) {
#pragma unroll
        for (int off = 1; off < 16; off <<= 1) {
          ps[hh] += __shfl_xor(ps[hh], off);
          pd[hh] += __shfl_xor(pd[hh], off);
        }
      }
      float vs = (l15 == 0) ? ps[0] : (l15 == 1) ? ps[1] : (l15 == 2) ? ps[2] : ps[3];
      float vd = (l15 == 0) ? pd[0] : (l15 == 1) ? pd[1] : (l15 == 2) ? pd[2] : pd[3];
      if (ok && l15 < 4) {
        os[grow * 4 + l15] = vs;
        od[grow * 4 + l15] = vd;
      }
    } else {
      float ps = 0.f, pd = 0.f;
#pragma unroll
      for (int ct = 0; ct < 8; ct++) {
        ps += acc[ct][r] * as_l[ct];
        pd += acc[ct][r] * ad_l[ct];
      }
#pragma unroll
      for (int off = 1; off < 16; off <<= 1) {
        ps += __shfl_xor(ps, off);
        pd += __shfl_xor(pd, off);
      }
      if (ok && l15 == 0) {
        os[grow] = ps;
        od[grow] = pd;
      }
    }
  }
}

// ---------------- bucket-sort CSR build ----------------
// pass A: LDS-aggregated bucket histogram
__global__ __launch_bounds__(256) void histb_k(const int* __restrict__ ei,
                                               int* __restrict__ bcnt) {
  __shared__ int h[NBK];
  const int t = threadIdx.x;
  for (int i = t; i < NBK; i += 256) h[i] = 0;
  __syncthreads();
#pragma unroll
  for (int ii = 0; ii < 4; ii++) {
    int e = blockIdx.x * 1024 + ii * 256 + t;
    if (e < ET) {
      int d = (e < NE) ? ei[NE + e] : e - NE;
      atomicAdd(&h[d >> SH], 1);
    }
  }
  __syncthreads();
  for (int i = t; i < NBK; i += 256) {
    int v = h[i];
    if (v) atomicAdd(&bcnt[i], v);
  }
}

// pass B: exclusive scan of 782 bucket counts (single block)
__global__ __launch_bounds__(1024) void scanb_k(const int* __restrict__ bcnt,
                                                int* __restrict__ bbase,
                                                int* __restrict__ bpos) {
  __shared__ int tmp[1024];
  const int t = threadIdx.x;
  int v = (t < NBK) ? bcnt[t] : 0;
  tmp[t] = v;
  __syncthreads();
  for (int off = 1; off < 1024; off <<= 1) {
    int x = (t >= off) ? tmp[t - off] : 0;
    __syncthreads();
    tmp[t] += x;
    __syncthreads();
  }
  if (t < NBK) {
    int excl = tmp[t] - v;
    bbase[t] = excl;
    bpos[t] = excl;
  }
  if (t == 0) bbase[NBK] = ET;
}

// pass C: scatter (src,dst) pairs into bucket-ordered tmp
__global__ __launch_bounds__(256) void scatterb_k(const int* __restrict__ ei,
                                                  int* __restrict__ bpos,
                                                  int2* __restrict__ tmpe) {
  int e = blockIdx.x * 256 + threadIdx.x;
  if (e >= ET) return;
  int s, d;
  if (e < NE) { s = ei[e]; d = ei[NE + e]; } else { s = d = e - NE; }
  int p = atomicAdd(&bpos[d >> SH], 1);
  int2 v; v.x = s; v.y = d;
  tmpe[p] = v;
}

// pass D: per-bucket local sort -> rowptr + srcs (block owns bucket exclusively)
__global__ __launch_bounds__(256) void bucket_build_k(
    const int2* __restrict__ tmpe, const int* __restrict__ bbase,
    int* __restrict__ rowptr, int* __restrict__ srcs) {
  const int b = blockIdx.x;
  const int t = threadIdx.x;
  const int base = bbase[b], end = bbase[b + 1];
  const int n0 = b << SH;
  __shared__ int cnt[128];
  __shared__ int off[128];
  if (t < 128) cnt[t] = 0;
  __syncthreads();
  for (int i = base + t; i < end; i += 256) {
    atomicAdd(&cnt[tmpe[i].y - n0], 1);
  }
  __syncthreads();
  if (t < 128) off[t] = cnt[t];
  __syncthreads();
  for (int s = 1; s < 128; s <<= 1) {
    int x = (t < 128 && t >= s) ? off[t - s] : 0;
    __syncthreads();
    if (t < 128) off[t] += x;
    __syncthreads();
  }
  if (t < 128) {
    int excl = base + off[t] - cnt[t];
    int node = n0 + t;
    if (node < NN) rowptr[node] = excl;
    cnt[t] = excl;  // reuse as write cursor
  }
  __syncthreads();
  for (int i = base + t; i < end; i += 256) {
    int2 v = tmpe[i];
    int p = atomicAdd(&cnt[v.y - n0], 1);
    srcs[p] = v.x;
  }
  if (b == 0 && t == 0) rowptr[NN] = ET;
}

// ---------------- GAT aggregation: one wave per dst node ----------------
template <int H, int C>
__global__ __launch_bounds__(64) void gat_agg_k(
    const int* __restrict__ rowptr, const int* __restrict__ srcs,
    const float* __restrict__ as, const float* __restrict__ ad,
    const unsigned short* __restrict__ h2, const float* __restrict__ bvec,
    float* __restrict__ y) {
  const int d = blockIdx.x;
  const int t = threadIdx.x;
  const int l15 = t & 15, g4 = t >> 4;
  const int r0 = rowptr[d], r1 = rowptr[d + 1];

  __shared__ int ssh[64];
  __shared__ float exsh[64 * H];

  float adl[H];
#pragma unroll
  for (int hh = 0; hh < H; hh++) adl[hh] = ad[d * H + hh];

  const int hc = (l15 * 8) / C;
  float acc[8];
#pragma unroll
  for (int i = 0; i < 8; i++) acc[i] = 0.f;
  float dsum[H];
#pragma unroll
  for (int hh = 0; hh < H; hh++) dsum[hh] = 0.f;

  const uint4* h4 = (const uint4*)h2;

  for (int base = r0; base < r1; base += 64) {
    int cnt = min(64, r1 - base);
    __syncthreads();
    if (t < cnt) {
      int s = srcs[base + t];
      ssh[t] = s;
      if (H == 4) {
        float4 av = *(const float4*)(as + s * 4);
        float lg, ex;
        lg = av.x + adl[0]; lg = lg > 0.f ? lg : 0.2f * lg; ex = __expf(lg);
        exsh[t * 4 + 0] = ex; dsum[0] += ex;
        lg = av.y + adl[1]; lg = lg > 0.f ? lg : 0.2f * lg; ex = __expf(lg);
        exsh[t * 4 + 1] = ex; dsum[1] += ex;
        lg = av.z + adl[2]; lg = lg > 0.f ? lg : 0.2f * lg; ex = __expf(lg);
        exsh[t * 4 + 2] = ex; dsum[2] += ex;
        lg = av.w + adl[3]; lg = lg > 0.f ? lg : 0.2f * lg; ex = __expf(lg);
        exsh[t * 4 + 3] = ex; dsum[3] += ex;
      } else {
        float lg = as[s] + adl[0];
        lg = lg > 0.f ? lg : 0.2f * lg;
        float ex = __expf(lg);
        exsh[t] = ex;
        dsum[0] += ex;
      }
    }
    __syncthreads();
    int full = cnt >> 2;
#pragma unroll 2
    for (int jj = 0; jj < full; jj++) {
      int grp = jj * 4 + g4;
      int row = ssh[grp];
      uint4 u = h4[(size_t)row * 16 + l15];
      float wgt = exsh[grp * H + hc];
      acc[0] += wgt * bf16lo(u.x);
      acc[1] += wgt * bf16hi(u.x);
      acc[2] += wgt * bf16lo(u.y);
      acc[3] += wgt * bf16hi(u.y);
      acc[4] += wgt * bf16lo(u.z);
      acc[5] += wgt * bf16hi(u.z);
      acc[6] += wgt * bf16lo(u.w);
      acc[7] += wgt * bf16hi(u.w);
    }
    if (cnt & 3) {
      int grp = full * 4 + g4;
      if (g4 < (cnt & 3)) {
        int row = ssh[grp];
        uint4 u = h4[(size_t)row * 16 + l15];
        float wgt = exsh[grp * H + hc];
        acc[0] += wgt * bf16lo(u.x);
        acc[1] += wgt * bf16hi(u.x);
        acc[2] += wgt * bf16lo(u.y);
        acc[3] += wgt * bf16hi(u.y);
        acc[4] += wgt * bf16lo(u.z);
        acc[5] += wgt * bf16hi(u.z);
        acc[6] += wgt * bf16lo(u.w);
        acc[7] += wgt * bf16hi(u.w);
      }
    }
  }

#pragma unroll
  for (int i = 0; i < 8; i++) {
    acc[i] += __shfl_xor(acc[i], 16);
    acc[i] += __shfl_xor(acc[i], 32);
  }
#pragma unroll
  for (int hh = 0; hh < H; hh++) {
#pragma unroll
    for (int off = 1; off < 64; off <<= 1) dsum[hh] += __shfl_xor(dsum[hh], off);
  }

  if (t < 16) {
    float inv = 1.f / (dsum[hc] + 1e-16f);
    float4 b0 = *(const float4*)(bvec + t * 8);
    float4 b1 = *(const float4*)(bvec + t * 8 + 4);
    float4 o0, o1;
    o0.x = acc[0] * inv + b0.x;
    o0.y = acc[1] * inv + b0.y;
    o0.z = acc[2] * inv + b0.z;
    o0.w = acc[3] * inv + b0.w;
    o1.x = acc[4] * inv + b1.x;
    o1.y = acc[5] * inv + b1.y;
    o1.z = acc[6] * inv + b1.z;
    o1.w = acc[7] * inv + b1.w;
    *(float4*)(y + (size_t)d * 128 + t * 8) = o0;
    *(float4*)(y + (size_t)d * 128 + t * 8 + 4) = o1;
  }
}

// ---------------- BN ----------------
__global__ __launch_bounds__(256) void bn_stats_k(const float* __restrict__ y,
                                                  float* __restrict__ bnred) {
  __shared__ float red[256];
  int c = threadIdx.x & 127;
  int sub = threadIdx.x >> 7;
  int n0 = blockIdx.x * 64;
  float s1 = 0.f, s2 = 0.f;
  for (int k = 0; k < 32; k++) {
    int n = n0 + sub + k * 2;
    if (n < NN) {
      float v = y[(size_t)n * 128 + c];
      s1 += v;
      s2 += v * v;
    }
  }
  red[threadIdx.x] = s1;
  __syncthreads();
  if (sub == 0) atomicAdd(&bnred[c], s1 + red[threadIdx.x + 128]);
  __syncthreads();
  red[threadIdx.x] = s2;
  __syncthreads();
  if (sub == 0) atomicAdd(&bnred[128 + c], s2 + red[threadIdx.x + 128]);
}

__global__ void bn2_k(const float* __restrict__ bnred, const float* __restrict__ g,
                      const float* __restrict__ be, float* __restrict__ scale,
                      float* __restrict__ shift) {
  int c = threadIdx.x;
  float mean = bnred[c] / (float)NN;
  float var = bnred[128 + c] / (float)NN - mean * mean;
  float inv = rsqrtf(var + 1e-5f);
  float sc = g[c] * inv;
  scale[c] = sc;
  shift[c] = be[c] - mean * sc;
}

__global__ void bn3_k(const float* __restrict__ y, const float* __restrict__ scale,
                      const float* __restrict__ shift, float* __restrict__ out) {
  int i = blockIdx.x * blockDim.x + threadIdx.x;
  if (i >= NN * 128) return;
  int c = i & 127;
  float v = y[i] * scale[c] + shift[c];
  out[i] = v > 0.f ? v : 0.f;
}

extern "C" void kernel_launch(void* const* d_in, const int* in_sizes, int n_in,
                              void* d_out, int out_size, void* d_ws, size_t ws_size,
                              hipStream_t stream) {
  (void)in_sizes; (void)n_in; (void)out_size; (void)ws_size;
  const float* x = (const float*)d_in[0];
  const int* ei = (const int*)d_in[1];
  const float* W1 = (const float*)d_in[2];
  const float* as1 = (const float*)d_in[3];
  const float* ad1 = (const float*)d_in[4];
  const float* b1 = (const float*)d_in[5];
  const float* g1 = (const float*)d_in[6];
  const float* be1 = (const float*)d_in[7];
  const float* W2 = (const float*)d_in[8];
  const float* as2 = (const float*)d_in[9];
  const float* ad2 = (const float*)d_in[10];
  const float* b2 = (const float*)d_in[11];
  const float* g2 = (const float*)d_in[12];
  const float* be2 = (const float*)d_in[13];
  const float* W3 = (const float*)d_in[14];
  const float* as3 = (const float*)d_in[15];
  const float* ad3 = (const float*)d_in[16];
  const float* b3 = (const float*)d_in[17];
  const float* g3 = (const float*)d_in[18];
  const float* be3 = (const float*)d_in[19];

  float* Y = (float*)d_ws;                                       // [NN*128] fp32
  unsigned short* h2 = (unsigned short*)(Y + (size_t)NN * 128);  // [NN*128] bf16
  unsigned short* xb = h2 + (size_t)NN * 128;                    // [NN*128] bf16
  float* asrc = (float*)(xb + (size_t)NN * 128);                 // [NN*4]
  float* adst = asrc + (size_t)NN * 4;                           // [NN*4]
  float* bnred = adst + (size_t)NN * 4;                          // [256]
  float* scale = bnred + 256;                                    // [128]
  float* shift = scale + 128;                                    // [128]
  int* rowptr = (int*)(shift + 128);                             // [NN+1]
  int* bcnt = rowptr + NN + 2;                                   // [NBK]
  int* bbase = bcnt + NBK;                                       // [NBK+1]
  int* bpos = bbase + NBK + 2;                                   // [NBK]
  int* srcs = bpos + NBK;                                        // [ET]
  int2* tmpe = (int2*)(srcs + ET + 2);                           // [ET] 8B each

  const int GB64 = (NN + 63) / 64;  // 1563

  // ---- bucket-sort CSR build ----
  hipMemsetAsync(bcnt, 0, NBK * sizeof(int), stream);
  histb_k<<<(ET + 1023) / 1024, 256, 0, stream>>>(ei, bcnt);
  scanb_k<<<1, 1024, 0, stream>>>(bcnt, bbase, bpos);
  scatterb_k<<<(ET + 255) / 256, 256, 0, stream>>>(ei, bpos, tmpe);
  bucket_build_k<<<NBK, 256, 0, stream>>>(tmpe, bbase, rowptr, srcs);

  // ---- Layer 1 ----
  castbf_k<<<(NN * 16 + 255) / 256, 256, 0, stream>>>(x, xb, NN * 16);
  gemm_mfma_k<64, 4><<<GB64, 256, 0, stream>>>(xb, W1, as1, ad1, h2, asrc, adst);
  gat_agg_k<4, 32><<<NN, 64, 0, stream>>>(rowptr, srcs, asrc, adst, h2, b1, Y);
  hipMemsetAsync(bnred, 0, 256 * sizeof(float), stream);
  bn_stats_k<<<GB64, 256, 0, stream>>>(Y, bnred);
  bn2_k<<<1, 128, 0, stream>>>(bnred, g1, be1, scale, shift);

  // ---- Layer 2 ----
  bnc_k<<<(NN * 32 + 255) / 256, 256, 0, stream>>>(Y, scale, shift, xb);
  gemm_mfma_k<128, 4><<<GB64, 256, 0, stream>>>(xb, W2, as2, ad2, h2, asrc, adst);
  gat_agg_k<4, 32><<<NN, 64, 0, stream>>>(rowptr, srcs, asrc, adst, h2, b2, Y);
  hipMemsetAsync(bnred, 0, 256 * sizeof(float), stream);
  bn_stats_k<<<GB64, 256, 0, stream>>>(Y, bnred);
  bn2_k<<<1, 128, 0, stream>>>(bnred, g2, be2, scale, shift);

  // ---- Layer 3 ----
  bnc_k<<<(NN * 32 + 255) / 256, 256, 0, stream>>>(Y, scale, shift, xb);
  gemm_mfma_k<128, 1><<<GB64, 256, 0, stream>>>(xb, W3, as3, ad3, h2, asrc, adst);
  gat_agg_k<1, 128><<<NN, 64, 0, stream>>>(rowptr, srcs, asrc, adst, h2, b3, Y);
  hipMemsetAsync(bnred, 0, 256 * sizeof(float), stream);
  bn_stats_k<<<GB64, 256, 0, stream>>>(Y, bnred);
  bn2_k<<<1, 128, 0, stream>>>(bnred, g3, be3, scale, shift);
  bn3_k<<<(NN * 128 + 255) / 256, 256, 0, stream>>>(Y, scale, shift, (float*)d_out);
}

// Round 6
// 603.458 us; speedup vs baseline: 1.6754x; 1.6754x over previous
//
#include <hip/hip_runtime.h>
#include <math.h>

#define NN 100000
#define NE 1600000
#define ET (NN + NE)
#define NBK2 391   // buckets of 256 nodes
#define EPB 8192   // edges per binscatter block
#define NGAT 2048

typedef __attribute__((ext_vector_type(8))) __bf16 bf16x8;
typedef __attribute__((ext_vector_type(4))) float f32x4;

__device__ __forceinline__ unsigned short bf16rne(float f) {
  unsigned u = __float_as_uint(f);
  unsigned r = u + 0x7fffu + ((u >> 16) & 1u);
  return (unsigned short)(r >> 16);
}
__device__ __forceinline__ float bf16lo(unsigned u) {
  return __uint_as_float(u << 16);
}
__device__ __forceinline__ float bf16hi(unsigned u) {
  return __uint_as_float(u & 0xffff0000u);
}

// ---------------- MFMA GEMM: h2 = bf16(BN?(src) @ W) + fused alpha dots ----------------
// src is fp32; staging applies optional BN(scale,shift)+ReLU, converts bf16 into
// XOR-swizzled LDS. 64 rows x 128 cols per block, 4 waves.
template <int K, int H, bool BN>
__global__ __launch_bounds__(256) void gemm_mfma_k(
    const float* __restrict__ xf, const float* __restrict__ W,
    const float* __restrict__ scale, const float* __restrict__ shift,
    const float* __restrict__ a_s, const float* __restrict__ a_d,
    unsigned short* __restrict__ h2, float* __restrict__ os,
    float* __restrict__ od) {
  __shared__ unsigned short xs[64 * K];
  __shared__ unsigned short Wt[128 * K];
  const int t = threadIdx.x;
  const int w = t >> 6;
  const int l = t & 63;
  const int l15 = l & 15, g = l >> 4;
  const int row0 = blockIdx.x * 64;

  // stage Wt[c][k] = bf16(W[k*128+c]), swizzled
  for (int idx = t; idx < K * 128; idx += 256) {
    int k = idx >> 7, c = idx & 127;
    unsigned byteoff = ((unsigned)(c * K + k) * 2u) ^ ((unsigned)(c & 7) << 4);
    *(unsigned short*)((char*)Wt + byteoff) = bf16rne(W[idx]);
  }
  // stage xs rows from fp32 with optional BN+ReLU, swizzled
  for (int idx = t; idx < 64 * (K / 8); idx += 256) {
    int r = idx / (K / 8);
    int c8 = (idx % (K / 8)) * 8;
    int grow = row0 + r;
    uint4 v = {0u, 0u, 0u, 0u};
    if (grow < NN) {
      float4 f0 = *(const float4*)(xf + (size_t)grow * K + c8);
      float4 f1 = *(const float4*)(xf + (size_t)grow * K + c8 + 4);
      if (BN) {
        float4 sc0 = *(const float4*)(scale + c8);
        float4 sc1 = *(const float4*)(scale + c8 + 4);
        float4 sh0 = *(const float4*)(shift + c8);
        float4 sh1 = *(const float4*)(shift + c8 + 4);
        f0.x = fmaxf(fmaf(f0.x, sc0.x, sh0.x), 0.f);
        f0.y = fmaxf(fmaf(f0.y, sc0.y, sh0.y), 0.f);
        f0.z = fmaxf(fmaf(f0.z, sc0.z, sh0.z), 0.f);
        f0.w = fmaxf(fmaf(f0.w, sc0.w, sh0.w), 0.f);
        f1.x = fmaxf(fmaf(f1.x, sc1.x, sh1.x), 0.f);
        f1.y = fmaxf(fmaf(f1.y, sc1.y, sh1.y), 0.f);
        f1.z = fmaxf(fmaf(f1.z, sc1.z, sh1.z), 0.f);
        f1.w = fmaxf(fmaf(f1.w, sc1.w, sh1.w), 0.f);
      }
      v.x = (unsigned)bf16rne(f0.x) | ((unsigned)bf16rne(f0.y) << 16);
      v.y = (unsigned)bf16rne(f0.z) | ((unsigned)bf16rne(f0.w) << 16);
      v.z = (unsigned)bf16rne(f1.x) | ((unsigned)bf16rne(f1.y) << 16);
      v.w = (unsigned)bf16rne(f1.z) | ((unsigned)bf16rne(f1.w) << 16);
    }
    unsigned byteoff = ((unsigned)(r * K + c8) * 2u) ^ ((unsigned)(r & 7) << 4);
    *(uint4*)((char*)xs + byteoff) = v;
  }
  __syncthreads();

  f32x4 acc[8];
#pragma unroll
  for (int ct = 0; ct < 8; ct++) acc[ct] = {0.f, 0.f, 0.f, 0.f};

  const int R = w * 16 + l15;
#pragma unroll
  for (int kc = 0; kc < K; kc += 32) {
    bf16x8 a = *(const bf16x8*)((const char*)xs +
        ((((unsigned)(R * K + kc + 8 * g)) * 2u) ^ ((unsigned)(R & 7) << 4)));
#pragma unroll
    for (int ct = 0; ct < 8; ct++) {
      int c = ct * 16 + l15;
      bf16x8 b = *(const bf16x8*)((const char*)Wt +
          ((((unsigned)(c * K + kc + 8 * g)) * 2u) ^ ((unsigned)(c & 7) << 4)));
      acc[ct] = __builtin_amdgcn_mfma_f32_16x16x32_bf16(a, b, acc[ct], 0, 0, 0);
    }
  }

  float as_l[8], ad_l[8];
#pragma unroll
  for (int ct = 0; ct < 8; ct++) {
    as_l[ct] = a_s[ct * 16 + l15];
    ad_l[ct] = a_d[ct * 16 + l15];
  }

#pragma unroll
  for (int r = 0; r < 4; r++) {
    int grow = row0 + w * 16 + 4 * g + r;
    bool ok = grow < NN;
    if (ok) {
#pragma unroll
      for (int ct = 0; ct < 8; ct++)
        h2[(size_t)grow * 128 + ct * 16 + l15] = bf16rne(acc[ct][r]);
    }
    if (H == 4) {
      float ps[4], pd[4];
#pragma unroll
      for (int hh = 0; hh < 4; hh++) {
        ps[hh] = acc[2 * hh][r] * as_l[2 * hh] + acc[2 * hh + 1][r] * as_l[2 * hh + 1];
        pd[hh] = acc[2 * hh][r] * ad_l[2 * hh] + acc[2 * hh + 1][r] * ad_l[2 * hh + 1];
      }
#pragma unroll
      for (int hh = 0; hh < 4; hh++) {
#pragma unroll
        for (int off = 1; off < 16; off <<= 1) {
          ps[hh] += __shfl_xor(ps[hh], off);
          pd[hh] += __shfl_xor(pd[hh], off);
        }
      }
      float vs = (l15 == 0) ? ps[0] : (l15 == 1) ? ps[1] : (l15 == 2) ? ps[2] : ps[3];
      float vd = (l15 == 0) ? pd[0] : (l15 == 1) ? pd[1] : (l15 == 2) ? pd[2] : pd[3];
      if (ok && l15 < 4) {
        os[grow * 4 + l15] = vs;
        od[grow * 4 + l15] = vd;
      }
    } else {
      float ps = 0.f, pd = 0.f;
#pragma unroll
      for (int ct = 0; ct < 8; ct++) {
        ps += acc[ct][r] * as_l[ct];
        pd += acc[ct][r] * ad_l[ct];
      }
#pragma unroll
      for (int off = 1; off < 16; off <<= 1) {
        ps += __shfl_xor(ps, off);
        pd += __shfl_xor(pd, off);
      }
      if (ok && l15 == 0) {
        os[grow] = ps;
        od[grow] = pd;
      }
    }
  }
}

// ---------------- CSR build: block-aggregated two-level bucket sort ----------------
// A: bucket-level histogram (LDS aggregated)
__global__ __launch_bounds__(256) void histb2_k(const int* __restrict__ ei,
                                                int* __restrict__ bcnt) {
  __shared__ int h[NBK2];
  const int t = threadIdx.x;
  for (int i = t; i < NBK2; i += 256) h[i] = 0;
  __syncthreads();
#pragma unroll
  for (int k = 0; k < 4; k++) {
    int e = blockIdx.x * 1024 + k * 256 + t;
    if (e < ET) {
      int d = (e < NE) ? ei[NE + e] : e - NE;
      atomicAdd(&h[d >> 8], 1);
    }
  }
  __syncthreads();
  for (int i = t; i < NBK2; i += 256)
    if (h[i]) atomicAdd(&bcnt[i], h[i]);
}

// B: exclusive scan of bucket counts
__global__ __launch_bounds__(512) void scanb2_k(const int* __restrict__ bcnt,
                                                int* __restrict__ bbase,
                                                int* __restrict__ gpos) {
  __shared__ int tmp[512];
  const int t = threadIdx.x;
  int v = (t < NBK2) ? bcnt[t] : 0;
  tmp[t] = v;
  __syncthreads();
  for (int off = 1; off < 512; off <<= 1) {
    int x = (t >= off) ? tmp[t - off] : 0;
    __syncthreads();
    tmp[t] += x;
    __syncthreads();
  }
  if (t < NBK2) {
    int e = tmp[t] - v;
    bbase[t] = e;
    gpos[t] = e;
  }
  if (t == 0) bbase[NBK2] = ET;
}

// C: block-aggregated binned scatter; each block reserves private per-bucket ranges
__global__ __launch_bounds__(256) void binscatter_k(const int* __restrict__ ei,
                                                    int* __restrict__ gpos,
                                                    int2* __restrict__ tmpe) {
  __shared__ int cnt[NBK2];
  __shared__ int cur[NBK2];
  const int t = threadIdx.x;
  for (int i = t; i < NBK2; i += 256) cnt[i] = 0;
  __syncthreads();
  const int e0 = blockIdx.x * EPB;
  const int e1 = min(ET, e0 + EPB);
  for (int e = e0 + t; e < e1; e += 256) {
    int d = (e < NE) ? ei[NE + e] : e - NE;
    atomicAdd(&cnt[d >> 8], 1);
  }
  __syncthreads();
  for (int i = t; i < NBK2; i += 256) {
    int c = cnt[i];
    cur[i] = c ? atomicAdd(&gpos[i], c) : 0;
  }
  __syncthreads();
  for (int e = e0 + t; e < e1; e += 256) {
    int s, d;
    if (e < NE) { s = ei[e]; d = ei[NE + e]; } else { s = d = e - NE; }
    int p = atomicAdd(&cur[d >> 8], 1);
    int2 v; v.x = s; v.y = d;
    tmpe[p] = v;
  }
}

// D: per-bucket build of rowptr + srcs (block owns a private 256-node range)
__global__ __launch_bounds__(256) void bucket_build2_k(
    const int2* __restrict__ tmpe, const int* __restrict__ bbase,
    int* __restrict__ rowptr, int* __restrict__ srcs) {
  const int b = blockIdx.x;
  const int t = threadIdx.x;
  const int base = bbase[b], end = bbase[b + 1];
  const int n0 = b << 8;
  __shared__ int cnt[256];
  __shared__ int off[256];
  cnt[t] = 0;
  __syncthreads();
  for (int i = base + t; i < end; i += 256) atomicAdd(&cnt[tmpe[i].y - n0], 1);
  __syncthreads();
  int myc = cnt[t];
  off[t] = myc;
  __syncthreads();
  for (int s = 1; s < 256; s <<= 1) {
    int x = (t >= s) ? off[t - s] : 0;
    __syncthreads();
    off[t] += x;
    __syncthreads();
  }
  int excl = base + off[t] - myc;
  int node = n0 + t;
  if (node < NN) rowptr[node] = excl;
  cnt[t] = excl;  // reuse as write cursor
  __syncthreads();
  for (int i = base + t; i < end; i += 256) {
    int2 v = tmpe[i];
    int p = atomicAdd(&cnt[v.y - n0], 1);
    srcs[p] = v.x;
  }
  if (b == 0 && t == 0) rowptr[NN] = ET;
}

// ---------------- GAT aggregation: persistent, one wave per node, fused BN stats ----------------
template <int H, int C>
__global__ __launch_bounds__(256) void gat_agg_k(
    const int* __restrict__ rowptr, const int* __restrict__ srcs,
    const float* __restrict__ as, const float* __restrict__ ad,
    const unsigned short* __restrict__ h2, const float* __restrict__ bvec,
    float* __restrict__ y, float* __restrict__ bnred) {
  const int t = threadIdx.x;
  const int wv = t >> 6, l = t & 63;
  const int l15 = l & 15, g4 = l >> 4;
  __shared__ int ssh[4][64];
  __shared__ float exsh[4][64 * H];
  __shared__ float bna[256];
  bna[t] = 0.f;
  __syncthreads();

  const int hc = (l15 * 8) / C;
  float s1[8], s2[8];
#pragma unroll
  for (int i = 0; i < 8; i++) { s1[i] = 0.f; s2[i] = 0.f; }

  float4 bv0 = {0, 0, 0, 0}, bv1 = {0, 0, 0, 0};
  if (l < 16) {
    bv0 = *(const float4*)(bvec + l * 8);
    bv1 = *(const float4*)(bvec + l * 8 + 4);
  }

  const uint4* h4 = (const uint4*)h2;
  const int gw = blockIdx.x * 4 + wv;
  const int NW = NGAT * 4;

  for (int d = gw; d < NN; d += NW) {
    const int r0 = rowptr[d], r1 = rowptr[d + 1];
    float adl[H];
#pragma unroll
    for (int hh = 0; hh < H; hh++) adl[hh] = ad[d * H + hh];
    float acc[8];
#pragma unroll
    for (int i = 0; i < 8; i++) acc[i] = 0.f;
    float dsum[H];
#pragma unroll
    for (int hh = 0; hh < H; hh++) dsum[hh] = 0.f;

    for (int base = r0; base < r1; base += 64) {
      int cnt = min(64, r1 - base);
      __builtin_amdgcn_wave_barrier();
      if (l < cnt) {
        int s = srcs[base + l];
        ssh[wv][l] = s;
        if (H == 4) {
          float4 av = *(const float4*)(as + s * 4);
          float lg, ex;
          lg = av.x + adl[0]; lg = lg > 0.f ? lg : 0.2f * lg; ex = __expf(lg);
          exsh[wv][l * 4 + 0] = ex; dsum[0] += ex;
          lg = av.y + adl[1]; lg = lg > 0.f ? lg : 0.2f * lg; ex = __expf(lg);
          exsh[wv][l * 4 + 1] = ex; dsum[1] += ex;
          lg = av.z + adl[2]; lg = lg > 0.f ? lg : 0.2f * lg; ex = __expf(lg);
          exsh[wv][l * 4 + 2] = ex; dsum[2] += ex;
          lg = av.w + adl[3]; lg = lg > 0.f ? lg : 0.2f * lg; ex = __expf(lg);
          exsh[wv][l * 4 + 3] = ex; dsum[3] += ex;
        } else {
          float lg = as[s] + adl[0];
          lg = lg > 0.f ? lg : 0.2f * lg;
          float ex = __expf(lg);
          exsh[wv][l] = ex;
          dsum[0] += ex;
        }
      }
      __builtin_amdgcn_wave_barrier();
      int full = cnt >> 2;
      for (int jj = 0; jj < full; jj++) {
        int grp = jj * 4 + g4;
        int row = ssh[wv][grp];
        uint4 u = h4[(size_t)row * 16 + l15];
        float wgt = exsh[wv][grp * H + hc];
        acc[0] += wgt * bf16lo(u.x);
        acc[1] += wgt * bf16hi(u.x);
        acc[2] += wgt * bf16lo(u.y);
        acc[3] += wgt * bf16hi(u.y);
        acc[4] += wgt * bf16lo(u.z);
        acc[5] += wgt * bf16hi(u.z);
        acc[6] += wgt * bf16lo(u.w);
        acc[7] += wgt * bf16hi(u.w);
      }
      if (cnt & 3) {
        int grp = full * 4 + g4;
        if (g4 < (cnt & 3)) {
          int row = ssh[wv][grp];
          uint4 u = h4[(size_t)row * 16 + l15];
          float wgt = exsh[wv][grp * H + hc];
          acc[0] += wgt * bf16lo(u.x);
          acc[1] += wgt * bf16hi(u.x);
          acc[2] += wgt * bf16lo(u.y);
          acc[3] += wgt * bf16hi(u.y);
          acc[4] += wgt * bf16lo(u.z);
          acc[5] += wgt * bf16hi(u.z);
          acc[6] += wgt * bf16lo(u.w);
          acc[7] += wgt * bf16hi(u.w);
        }
      }
      __builtin_amdgcn_wave_barrier();
    }

#pragma unroll
    for (int i = 0; i < 8; i++) {
      acc[i] += __shfl_xor(acc[i], 16);
      acc[i] += __shfl_xor(acc[i], 32);
    }
#pragma unroll
    for (int hh = 0; hh < H; hh++) {
#pragma unroll
      for (int off = 1; off < 64; off <<= 1) dsum[hh] += __shfl_xor(dsum[hh], off);
    }

    if (l < 16) {
      float inv = 1.f / (dsum[hc] + 1e-16f);
      float o[8];
      o[0] = acc[0] * inv + bv0.x;
      o[1] = acc[1] * inv + bv0.y;
      o[2] = acc[2] * inv + bv0.z;
      o[3] = acc[3] * inv + bv0.w;
      o[4] = acc[4] * inv + bv1.x;
      o[5] = acc[5] * inv + bv1.y;
      o[6] = acc[6] * inv + bv1.z;
      o[7] = acc[7] * inv + bv1.w;
      float4 w0 = {o[0], o[1], o[2], o[3]};
      float4 w1 = {o[4], o[5], o[6], o[7]};
      *(float4*)(y + (size_t)d * 128 + l * 8) = w0;
      *(float4*)(y + (size_t)d * 128 + l * 8 + 4) = w1;
#pragma unroll
      for (int i = 0; i < 8; i++) {
        s1[i] += o[i];
        s2[i] += o[i] * o[i];
      }
    }
  }

  // merge BN partials: wave -> LDS -> global
  if (l < 16) {
#pragma unroll
    for (int i = 0; i < 8; i++) {
      atomicAdd(&bna[l15 * 8 + i], s1[i]);
      atomicAdd(&bna[128 + l15 * 8 + i], s2[i]);
    }
  }
  __syncthreads();
  atomicAdd(&bnred[t], bna[t]);
}

// ---------------- BN finalize ----------------
__global__ void bn2_k(const float* __restrict__ bnred, const float* __restrict__ g,
                      const float* __restrict__ be, float* __restrict__ scale,
                      float* __restrict__ shift) {
  int c = threadIdx.x;
  float mean = bnred[c] / (float)NN;
  float var = bnred[128 + c] / (float)NN - mean * mean;
  float inv = rsqrtf(var + 1e-5f);
  float sc = g[c] * inv;
  scale[c] = sc;
  shift[c] = be[c] - mean * sc;
}

__global__ void bn3_k(const float* __restrict__ y, const float* __restrict__ scale,
                      const float* __restrict__ shift, float* __restrict__ out) {
  int i = blockIdx.x * blockDim.x + threadIdx.x;
  if (i >= NN * 128) return;
  int c = i & 127;
  float v = y[i] * scale[c] + shift[c];
  out[i] = v > 0.f ? v : 0.f;
}

extern "C" void kernel_launch(void* const* d_in, const int* in_sizes, int n_in,
                              void* d_out, int out_size, void* d_ws, size_t ws_size,
                              hipStream_t stream) {
  (void)in_sizes; (void)n_in; (void)out_size; (void)ws_size;
  const float* x = (const float*)d_in[0];
  const int* ei = (const int*)d_in[1];
  const float* W1 = (const float*)d_in[2];
  const float* as1 = (const float*)d_in[3];
  const float* ad1 = (const float*)d_in[4];
  const float* b1 = (const float*)d_in[5];
  const float* g1 = (const float*)d_in[6];
  const float* be1 = (const float*)d_in[7];
  const float* W2 = (const float*)d_in[8];
  const float* as2 = (const float*)d_in[9];
  const float* ad2 = (const float*)d_in[10];
  const float* b2 = (const float*)d_in[11];
  const float* g2 = (const float*)d_in[12];
  const float* be2 = (const float*)d_in[13];
  const float* W3 = (const float*)d_in[14];
  const float* as3 = (const float*)d_in[15];
  const float* ad3 = (const float*)d_in[16];
  const float* b3 = (const float*)d_in[17];
  const float* g3 = (const float*)d_in[18];
  const float* be3 = (const float*)d_in[19];

  float* Y = (float*)d_ws;                                       // [NN*128] fp32
  unsigned short* h2 = (unsigned short*)(Y + (size_t)NN * 128);  // [NN*128] bf16
  int2* tmpe = (int2*)(h2 + (size_t)NN * 128);                   // [ET]
  float* asrc = (float*)(tmpe + (size_t)ET);                     // [NN*4]
  float* adst = asrc + (size_t)NN * 4;                           // [NN*4]
  float* bnred = adst + (size_t)NN * 4;                          // [256]
  float* scale = bnred + 256;                                    // [128]
  float* shift = scale + 128;                                    // [128]
  int* rowptr = (int*)(shift + 128);                             // [NN+2]
  int* bcnt = rowptr + NN + 2;                                   // [NBK2]
  int* bbase = bcnt + NBK2;                                      // [NBK2+1]
  int* gpos = bbase + NBK2 + 1;                                  // [NBK2]
  int* srcs = gpos + NBK2;                                       // [ET]

  const int GB64 = (NN + 63) / 64;  // 1563

  // ---- CSR build ----
  hipMemsetAsync(bcnt, 0, NBK2 * sizeof(int), stream);
  histb2_k<<<(ET + 1023) / 1024, 256, 0, stream>>>(ei, bcnt);
  scanb2_k<<<1, 512, 0, stream>>>(bcnt, bbase, gpos);
  binscatter_k<<<(ET + EPB - 1) / EPB, 256, 0, stream>>>(ei, gpos, tmpe);
  bucket_build2_k<<<NBK2, 256, 0, stream>>>(tmpe, bbase, rowptr, srcs);

  // ---- Layer 1 ----
  gemm_mfma_k<64, 4, false><<<GB64, 256, 0, stream>>>(x, W1, nullptr, nullptr,
                                                      as1, ad1, h2, asrc, adst);
  hipMemsetAsync(bnred, 0, 256 * sizeof(float), stream);
  gat_agg_k<4, 32><<<NGAT, 256, 0, stream>>>(rowptr, srcs, asrc, adst, h2, b1, Y, bnred);
  bn2_k<<<1, 128, 0, stream>>>(bnred, g1, be1, scale, shift);

  // ---- Layer 2 ----
  gemm_mfma_k<128, 4, true><<<GB64, 256, 0, stream>>>(Y, W2, scale, shift,
                                                      as2, ad2, h2, asrc, adst);
  hipMemsetAsync(bnred, 0, 256 * sizeof(float), stream);
  gat_agg_k<4, 32><<<NGAT, 256, 0, stream>>>(rowptr, srcs, asrc, adst, h2, b2, Y, bnred);
  bn2_k<<<1, 128, 0, stream>>>(bnred, g2, be2, scale, shift);

  // ---- Layer 3 ----
  gemm_mfma_k<128, 1, true><<<GB64, 256, 0, stream>>>(Y, W3, scale, shift,
                                                      as3, ad3, h2, asrc, adst);
  hipMemsetAsync(bnred, 0, 256 * sizeof(float), stream);
  gat_agg_k<1, 128><<<NGAT, 256, 0, stream>>>(rowptr, srcs, asrc, adst, h2, b3, Y, bnred);
  bn2_k<<<1, 128, 0, stream>>>(bnred, g3, be3, scale, shift);
  bn3_k<<<(NN * 128 + 255) / 256, 256, 0, stream>>>(Y, scale, shift, (float*)d_out);
}